// Round 2
// baseline (2601.305 us; speedup 1.0000x reference)
//
#include <hip/hip_runtime.h>
#include <hip/hip_bf16.h>
#include <hip/hip_fp16.h>

#define NB 8
#define NP 8192
#define NC 64
#define NM 2048
#define NK 32
#define RAD2 0.04f

typedef unsigned int u32;
typedef unsigned long long u64;
typedef _Float16 f16x8 __attribute__((ext_vector_type(8)));
typedef float f32x4 __attribute__((ext_vector_type(4)));
typedef float f32x2 __attribute__((ext_vector_type(2)));

// exact reference arithmetic: ((dx*dx + dy*dy) + dz*dz), no FMA contraction
__device__ __forceinline__ float d2e(float ax, float ay, float az,
                                     float bx, float by, float bz) {
    float dx = __fsub_rn(ax, bx), dy = __fsub_rn(ay, by), dz = __fsub_rn(az, bz);
    return __fadd_rn(__fadd_rn(__fmul_rn(dx, dx), __fmul_rn(dy, dy)), __fmul_rn(dz, dz));
}

// packed 2xf32 ops (CDNA VOP3P). Per-half IEEE-identical to scalar v_add/v_mul.
__device__ __forceinline__ f32x2 pk_add(f32x2 a, f32x2 b) {
    f32x2 d; asm("v_pk_add_f32 %0, %1, %2" : "=v"(d) : "v"(a), "v"(b)); return d;
}
__device__ __forceinline__ f32x2 pk_mul(f32x2 a, f32x2 b) {
    f32x2 d; asm("v_pk_mul_f32 %0, %1, %2" : "=v"(d) : "v"(a), "v"(b)); return d;
}

// one DPP combine level for (value desc, index asc) argmax
#define RED_LEVEL(CTRL) do {                                                          \
    float v2_ = __int_as_float(__builtin_amdgcn_update_dpp(                           \
        __float_as_int(bv), __float_as_int(bv), (CTRL), 0xF, 0xF, false));            \
    int p2_ = __builtin_amdgcn_update_dpp(bp, bp, (CTRL), 0xF, 0xF, false);           \
    bool take_ = (v2_ > bv) || ((v2_ == bv) && (p2_ < bp));                           \
    bv = take_ ? v2_ : bv;                                                            \
    bp = take_ ? p2_ : bp;                                                            \
} while (0)

// ---------------- Kernel 1: farthest point sampling (1 block per cloud) ----
__global__ __launch_bounds__(256, 1) void fps_kernel(const float* __restrict__ pos,
                                                     float* __restrict__ pos_s) {
    __shared__ float spos[NP * 3];
    __shared__ u64 rkey[2][4];
    const int b = blockIdx.x;
    const int tid = threadIdx.x;
    const int lane = tid & 63, wid = tid >> 6;
    const float* pb = pos + (size_t)b * (NP * 3);
    for (int i = tid; i < NP * 3; i += 256) spos[i] = pb[i];
    __syncthreads();

    f32x2 px[16], py[16], pz[16], mind2[16];
    const float s0x = spos[0], s0y = spos[1], s0z = spos[2];
    f32x2 nsx = {-s0x, -s0x}, nsy = {-s0y, -s0y}, nsz = {-s0z, -s0z};
    float cv[4]; int cp[4];
#pragma unroll
    for (int c = 0; c < 4; ++c) { cv[c] = -1.0f; cp[c] = 0; }
#pragma unroll
    for (int j = 0; j < 16; ++j) {
        int p0 = tid + (2 * j) * 256;
        px[j] = (f32x2){spos[3 * p0], spos[3 * (p0 + 256)]};
        py[j] = (f32x2){spos[3 * p0 + 1], spos[3 * (p0 + 256) + 1]};
        pz[j] = (f32x2){spos[3 * p0 + 2], spos[3 * (p0 + 256) + 2]};
        f32x2 dx = pk_add(px[j], nsx), dy = pk_add(py[j], nsy), dz = pk_add(pz[j], nsz);
        f32x2 d2 = pk_add(pk_add(pk_mul(dx, dx), pk_mul(dy, dy)), pk_mul(dz, dz));
        mind2[j] = d2;
        int c = j >> 2;
        if (d2.x > cv[c]) { cv[c] = d2.x; cp[c] = p0; }
        if (d2.y > cv[c]) { cv[c] = d2.y; cp[c] = p0 + 256; }
    }
    float* outp = pos_s + (size_t)b * (NM * 3);
    if (tid == 0) { outp[0] = s0x; outp[1] = s0y; outp[2] = s0z; }

    for (int t = 1; t < NM; ++t) {
        // combine 4 chains (ascending chain order, strict > => first-max kept)
        float bv = cv[0]; int bp = cp[0];
#pragma unroll
        for (int c = 1; c < 4; ++c) {
            if (cv[c] > bv) { bv = cv[c]; bp = cp[c]; }
        }
        // wave64 DPP argmax reduce -> lane 63
        RED_LEVEL(0x111);  // row_shr:1
        RED_LEVEL(0x112);  // row_shr:2
        RED_LEVEL(0x114);  // row_shr:4
        RED_LEVEL(0x118);  // row_shr:8
        RED_LEVEL(0x142);  // row_bcast:15
        RED_LEVEL(0x143);  // row_bcast:31
        float wv = __int_as_float(__builtin_amdgcn_readlane(__float_as_int(bv), 63));
        int wp = __builtin_amdgcn_readlane(bp, 63);
        u64 key = ((u64)__float_as_uint(wv) << 32) | (u32)(0xFFFFFFFFu - (u32)wp);
        if (lane == 0) rkey[t & 1][wid] = key;
        __syncthreads();
        u64 k0 = rkey[t & 1][0], k1 = rkey[t & 1][1];
        u64 k2 = rkey[t & 1][2], k3 = rkey[t & 1][3];
        if (k1 > k0) k0 = k1;
        if (k3 > k2) k2 = k3;
        if (k2 > k0) k0 = k2;
        const int nxt = (int)(0xFFFFFFFFu - (u32)k0);
        const float sx = spos[3 * nxt], sy = spos[3 * nxt + 1], sz = spos[3 * nxt + 2];
        if (tid == 0) { outp[3 * t] = sx; outp[3 * t + 1] = sy; outp[3 * t + 2] = sz; }
        nsx = (f32x2){-sx, -sx}; nsy = (f32x2){-sy, -sy}; nsz = (f32x2){-sz, -sz};
#pragma unroll
        for (int c = 0; c < 4; ++c) { cv[c] = -1.0f; cp[c] = 0; }
#pragma unroll
        for (int j = 0; j < 16; ++j) {
            f32x2 dx = pk_add(px[j], nsx), dy = pk_add(py[j], nsy), dz = pk_add(pz[j], nsz);
            f32x2 d2 = pk_add(pk_add(pk_mul(dx, dx), pk_mul(dy, dy)), pk_mul(dz, dz));
            f32x2 m = mind2[j];
            float n0 = fminf(m.x, d2.x), n1 = fminf(m.y, d2.y);
            mind2[j] = (f32x2){n0, n1};
            int c = j >> 2;
            if (n0 > cv[c]) { cv[c] = n0; cp[c] = tid + (2 * j) * 256; }
            if (n1 > cv[c]) { cv[c] = n1; cp[c] = tid + (2 * j) * 256 + 256; }
        }
    }
}

// ---------------- Kernel 2: radius-limited 32-NN (8 queries per block) -----
#define GQ 8
#define CAP 768
__global__ __launch_bounds__(256, 1) void knn_kernel(const float* __restrict__ pos,
                                                     const float* __restrict__ pos_s,
                                                     int* __restrict__ nbr) {
    __shared__ u64 keys[GQ][CAP];
    __shared__ int cnt[GQ];
    const int qbase = blockIdx.x * GQ;
    const int b = qbase >> 11;
    const int tid = threadIdx.x;
    if (tid < GQ) cnt[tid] = 0;
    for (int i = tid; i < GQ * NK; i += 256) nbr[qbase * NK + i] = -1;

    float qx[GQ], qy[GQ], qz[GQ];
#pragma unroll
    for (int q = 0; q < GQ; ++q) {
        qx[q] = pos_s[(qbase + q) * 3];
        qy[q] = pos_s[(qbase + q) * 3 + 1];
        qz[q] = pos_s[(qbase + q) * 3 + 2];
    }
    __syncthreads();

    const float* pb = pos + (size_t)b * (NP * 3);
    for (int i = 0; i < NP / 256; ++i) {
        int p = tid + (i << 8);
        float x = pb[3 * p], y = pb[3 * p + 1], z = pb[3 * p + 2];
#pragma unroll
        for (int q = 0; q < GQ; ++q) {
            float d = d2e(x, y, z, qx[q], qy[q], qz[q]);
            if (d <= RAD2) {
                int slot = atomicAdd(&cnt[q], 1);
                if (slot < CAP) keys[q][slot] = ((u64)__float_as_uint(d) << 32) | (u32)p;
            }
        }
    }
    __syncthreads();

    // exact rank selection: keys are unique (idx in low bits) -> stable top-k
    for (int q = 0; q < GQ; ++q) {
        int c = min(cnt[q], CAP);
        for (int j = tid; j < c; j += 256) {
            u64 key = keys[q][j];
            int rank = 0;
            for (int t2 = 0; t2 < c; ++t2) rank += (keys[q][t2] < key) ? 1 : 0;
            if (rank < NK) nbr[(qbase + q) * NK + rank] = (int)(u32)(key & 0xFFFFFFFFull);
        }
    }
}

// ---------------- Kernel 3: gather + MLP (fp16 MFMA) + masked max-pool -----
#define FPAD 104
#define HPAD 72
#define TG 8
__global__ __launch_bounds__(512, 1) void mlp_kernel(
    const float* __restrict__ x, const float* __restrict__ pos,
    const float* __restrict__ W0, const float* __restrict__ b0,
    const float* __restrict__ W1, const float* __restrict__ b1,
    const float* __restrict__ W2, const float* __restrict__ b2,
    const float* __restrict__ pos_s, const int* __restrict__ nbr,
    float* __restrict__ x1) {
    __shared__ _Float16 feat[256 * FPAD];   // reused as h2[256][HPAD] after GEMM1
    __shared__ _Float16 h1[256 * HPAD];
    __shared__ _Float16 wt0[64 * FPAD];
    __shared__ _Float16 wt1[64 * HPAD];
    __shared__ _Float16 wt2[128 * HPAD];
    __shared__ float bias0[64], bias1[64], bias2[128];
    __shared__ int vld[256];

    const int tid = threadIdx.x;
    const int g0 = blockIdx.x * TG;
    const int b = g0 >> 11;

    // stage weights transposed: wt[c][j] = W[j][c], zero-padded in K
    for (int idx = tid; idx < 64 * FPAD; idx += 512) {
        int c2 = idx / FPAD, j = idx - c2 * FPAD;
        wt0[idx] = (_Float16)((j < 67) ? W0[j * 64 + c2] : 0.0f);
    }
    for (int idx = tid; idx < 64 * HPAD; idx += 512) {
        int c2 = idx / HPAD, j = idx - c2 * HPAD;
        wt1[idx] = (_Float16)((j < 64) ? W1[j * 64 + c2] : 0.0f);
    }
    for (int idx = tid; idx < 128 * HPAD; idx += 512) {
        int c2 = idx / HPAD, j = idx - c2 * HPAD;
        wt2[idx] = (_Float16)((j < 64) ? W2[j * 128 + c2] : 0.0f);
    }
    if (tid < 64) { bias0[tid] = b0[tid]; bias1[tid] = b1[tid]; }
    else if (tid < 192) bias2[tid - 64] = b2[tid - 64];

    // gather features: 2 threads per row, rows = (group, k)
    {
        int r = tid >> 1, half = tid & 1;
        int g = g0 + (r >> 5), k = r & 31;
        int nid = nbr[g * NK + k];
        int nid2 = nid < 0 ? 0 : nid;
        const float* xr = x + ((size_t)b * NP + nid2) * NC + half * 32;
        _Float16* dst = &feat[r * FPAD + half * 32];
#pragma unroll
        for (int i = 0; i < 8; ++i) {
            float4 v = *(const float4*)(xr + i * 4);
            dst[i * 4 + 0] = (_Float16)v.x; dst[i * 4 + 1] = (_Float16)v.y;
            dst[i * 4 + 2] = (_Float16)v.z; dst[i * 4 + 3] = (_Float16)v.w;
        }
        if (half) {
            const float* pj = pos + ((size_t)b * NP + nid2) * 3;
            const float* ps = pos_s + (size_t)g * 3;
            feat[r * FPAD + 64] = (_Float16)(pj[0] - ps[0]);
            feat[r * FPAD + 65] = (_Float16)(pj[1] - ps[1]);
            feat[r * FPAD + 66] = (_Float16)(pj[2] - ps[2]);
#pragma unroll
            for (int j = 67; j < 96; ++j) feat[r * FPAD + j] = (_Float16)0.0f;
        } else {
            vld[r] = (nid >= 0) ? 1 : 0;
        }
    }
    __syncthreads();

    const int lane = tid & 63, w = tid >> 6;
    const int rb = w * 32;          // this wave owns one (b,m) group = 32 rows
    const int ar = lane & 15;
    const int kg = lane >> 4;

    // GEMM1: feat[256x96] x W0 -> h1[256x64], relu
    {
        f32x4 acc[2][4] = {};
#pragma unroll
        for (int kt = 0; kt < 3; ++kt) {
            f16x8 a0 = *(const f16x8*)&feat[(rb + ar) * FPAD + kt * 32 + kg * 8];
            f16x8 a1 = *(const f16x8*)&feat[(rb + 16 + ar) * FPAD + kt * 32 + kg * 8];
#pragma unroll
            for (int nt = 0; nt < 4; ++nt) {
                f16x8 bb = *(const f16x8*)&wt0[(nt * 16 + ar) * FPAD + kt * 32 + kg * 8];
                acc[0][nt] = __builtin_amdgcn_mfma_f32_16x16x32_f16(a0, bb, acc[0][nt], 0, 0, 0);
                acc[1][nt] = __builtin_amdgcn_mfma_f32_16x16x32_f16(a1, bb, acc[1][nt], 0, 0, 0);
            }
        }
#pragma unroll
        for (int mt = 0; mt < 2; ++mt)
#pragma unroll
            for (int nt = 0; nt < 4; ++nt)
#pragma unroll
                for (int ri = 0; ri < 4; ++ri) {
                    int row = rb + mt * 16 + kg * 4 + ri;
                    int col = nt * 16 + ar;
                    float v = fmaxf(acc[mt][nt][ri] + bias0[col], 0.0f);
                    h1[row * HPAD + col] = (_Float16)v;
                }
    }
    __syncthreads();

    // GEMM2: h1[256x64] x W1 -> h2 (reusing feat), relu
    _Float16* h2 = feat;
    {
        f32x4 acc[2][4] = {};
#pragma unroll
        for (int kt = 0; kt < 2; ++kt) {
            f16x8 a0 = *(const f16x8*)&h1[(rb + ar) * HPAD + kt * 32 + kg * 8];
            f16x8 a1 = *(const f16x8*)&h1[(rb + 16 + ar) * HPAD + kt * 32 + kg * 8];
#pragma unroll
            for (int nt = 0; nt < 4; ++nt) {
                f16x8 bb = *(const f16x8*)&wt1[(nt * 16 + ar) * HPAD + kt * 32 + kg * 8];
                acc[0][nt] = __builtin_amdgcn_mfma_f32_16x16x32_f16(a0, bb, acc[0][nt], 0, 0, 0);
                acc[1][nt] = __builtin_amdgcn_mfma_f32_16x16x32_f16(a1, bb, acc[1][nt], 0, 0, 0);
            }
        }
#pragma unroll
        for (int mt = 0; mt < 2; ++mt)
#pragma unroll
            for (int nt = 0; nt < 4; ++nt)
#pragma unroll
                for (int ri = 0; ri < 4; ++ri) {
                    int row = rb + mt * 16 + kg * 4 + ri;
                    int col = nt * 16 + ar;
                    float v = fmaxf(acc[mt][nt][ri] + bias1[col], 0.0f);
                    h2[row * HPAD + col] = (_Float16)v;
                }
    }
    __syncthreads();

    // GEMM3: h2[256x64] x W2 -> [256x128], relu + masked max-pool over k=32
    {
        f32x4 acc[2][8] = {};
#pragma unroll
        for (int kt = 0; kt < 2; ++kt) {
            f16x8 a0 = *(const f16x8*)&h2[(rb + ar) * HPAD + kt * 32 + kg * 8];
            f16x8 a1 = *(const f16x8*)&h2[(rb + 16 + ar) * HPAD + kt * 32 + kg * 8];
#pragma unroll
            for (int nt = 0; nt < 8; ++nt) {
                f16x8 bb = *(const f16x8*)&wt2[(nt * 16 + ar) * HPAD + kt * 32 + kg * 8];
                acc[0][nt] = __builtin_amdgcn_mfma_f32_16x16x32_f16(a0, bb, acc[0][nt], 0, 0, 0);
                acc[1][nt] = __builtin_amdgcn_mfma_f32_16x16x32_f16(a1, bb, acc[1][nt], 0, 0, 0);
            }
        }
        const int g = g0 + w;
#pragma unroll
        for (int nt = 0; nt < 8; ++nt) {
            int col = nt * 16 + ar;
            float bz = bias2[col];
            float bmax = 0.0f;   // h>=0 post-relu and self is always valid
#pragma unroll
            for (int mt = 0; mt < 2; ++mt)
#pragma unroll
                for (int ri = 0; ri < 4; ++ri) {
                    int row = rb + mt * 16 + kg * 4 + ri;
                    float v = fmaxf(acc[mt][nt][ri] + bz, 0.0f);
                    bmax = fmaxf(bmax, vld[row] ? v : 0.0f);
                }
            bmax = fmaxf(bmax, __shfl_xor(bmax, 16));
            bmax = fmaxf(bmax, __shfl_xor(bmax, 32));
            if (lane < 16) x1[(size_t)g * 128 + nt * 16 + lane] = bmax;
        }
    }
}

extern "C" void kernel_launch(void* const* d_in, const int* in_sizes, int n_in,
                              void* d_out, int out_size, void* d_ws, size_t ws_size,
                              hipStream_t stream) {
    const float* x   = (const float*)d_in[0];
    const float* pos = (const float*)d_in[1];
    const float* W0  = (const float*)d_in[2];
    const float* b0  = (const float*)d_in[3];
    const float* W1  = (const float*)d_in[4];
    const float* b1  = (const float*)d_in[5];
    const float* W2  = (const float*)d_in[6];
    const float* b2  = (const float*)d_in[7];
    float* x1    = (float*)d_out;
    float* pos_s = x1 + (size_t)NB * NM * 128;   // outputs concatenated: x1 then pos_s
    int* nbr = (int*)d_ws;                        // [NB*NM, NK] int32 = 2MB

    fps_kernel<<<NB, 256, 0, stream>>>(pos, pos_s);
    knn_kernel<<<(NB * NM) / GQ, 256, 0, stream>>>(pos, pos_s, nbr);
    mlp_kernel<<<(NB * NM) / TG, 512, 0, stream>>>(x, pos, W0, b0, W1, b1, W2, b2,
                                                   pos_s, nbr, x1);
}